// Round 8
// baseline (491.000 us; speedup 1.0000x reference)
//
#include <hip/hip_runtime.h>
#include <hip/hip_bf16.h>

typedef __bf16 bf16;
typedef __bf16 bf16x4 __attribute__((ext_vector_type(4)));
typedef __bf16 bf16x8 __attribute__((ext_vector_type(8)));
typedef float  f32x4  __attribute__((ext_vector_type(4)));
typedef signed char i8;
typedef signed char i8x4 __attribute__((ext_vector_type(4)));
typedef int    i32x4 __attribute__((ext_vector_type(4)));

#define DEVFN static __device__ __forceinline__

static constexpr int T_STEPS = 25;
static constexpr int BATCH   = 256;
static constexpr int MROWS   = T_STEPS * BATCH;  // 6400
static constexpr int RBS     = MROWS / 16;       // 400 row-tiles

// async global->LDS, 16B/lane; LDS base must be wave-uniform (HW adds lane*16).
DEVFN void llds16(const void* g, void* l) {
    __builtin_amdgcn_global_load_lds(
        (const __attribute__((address_space(1))) void*)g,
        (__attribute__((address_space(3))) void*)l, 16, 0, 0);
}

// ---------------------------------------------------------------------------
// Tiled A layouts (R8): A operands are stored in MFMA-fragment order so GEMMs
// read them straight from global (L2-resident) into VGPRs — LDS carries only B.
// Tile = 1KB covering [16 rows][K-chunk] with lane l's 16B at tile+l*16:
//   bf16 tile: 16 rows x 32 k  (kb = k>>5);  internal byte
//     ((k>>3)&3)*256 + (row&15)*16 + (k&7)*2
//   i8  tile: 16 rows x 64 k  (kb = k>>6);  internal byte
//     ((k>>4)&3)*256 + (row&15)*16 + (k&15)
// Tile array: [kb][rb = row>>4] (RBS=400 row-tiles). Both match the MFMA frag
// map row=lane&15, k-bytes=(lane>>4)*16 (verified by R7's passing i8 kernel).

// Precision splits (numerics unchanged from R7 — verified passing).
DEVFN void split3_w0(const float* src, bf16* p0, bf16* p1, bf16* p2, int i) {
    float4 v = *(const float4*)(src + i);
    float vv[4] = {v.x, v.y, v.z, v.w};
    bf16x4 a, b, c;
#pragma unroll
    for (int k = 0; k < 4; ++k) {
        bf16 h0 = (bf16)vv[k];
        float r1 = vv[k] - (float)h0;      // exact
        bf16 h1 = (bf16)r1;
        float r2 = r1 - (float)h1;         // exact
        a[k] = h0; b[k] = h1; c[k] = (bf16)r2;
    }
    *(bf16x4*)(p0 + i) = a;
    *(bf16x4*)(p1 + i) = b;
    *(bf16x4*)(p2 + i) = c;
}

// x split: same values, written TILED (row = i>>10, k = i&1023; 4 consec k).
DEVFN void split3_x(const float* src, char* p0, char* p1, char* p2, int i) {
    float4 v = *(const float4*)(src + i);
    float vv[4] = {v.x, v.y, v.z, v.w};
    bf16x4 a, b, c;
#pragma unroll
    for (int k = 0; k < 4; ++k) {
        bf16 h0 = (bf16)vv[k];
        float r1 = vv[k] - (float)h0;
        bf16 h1 = (bf16)r1;
        float r2 = r1 - (float)h1;
        a[k] = h0; b[k] = h1; c[k] = (bf16)r2;
    }
    int row = i >> 10, k = i & 1023;
    int off = ((((k >> 5) * RBS + (row >> 4)) << 10)
               | (((k >> 3) & 3) << 8) | ((row & 15) << 4) | ((k & 7) << 1));
    *(bf16x4*)(p0 + off) = a;
    *(bf16x4*)(p1 + off) = b;
    *(bf16x4*)(p2 + off) = c;
}

DEVFN void spliti8_3(const float* src, i8* p0, i8* p1, i8* p2, int i) {
    float4 v = *(const float4*)(src + i);
    float vv[4] = {v.x, v.y, v.z, v.w};
    i8x4 a, b, c;
#pragma unroll
    for (int k = 0; k < 4; ++k) {
        float t  = vv[k] * 4096.0f;              // exact (pow2)
        float q0 = rintf(t);  float r = t - q0;             // exact
        float q1 = rintf(r * 128.0f); r = r * 128.0f - q1;  // exact
        float q2 = rintf(r * 128.0f);
        a[k] = (i8)(int)q0; b[k] = (i8)(int)q1; c[k] = (i8)(int)q2;
    }
    *(i8x4*)(p0 + i) = a; *(i8x4*)(p1 + i) = b; *(i8x4*)(p2 + i) = c;
}

DEVFN void spliti8_2(const float* src, i8* p0, i8* p1, int i) {
    float4 v = *(const float4*)(src + i);
    float vv[4] = {v.x, v.y, v.z, v.w};
    i8x4 a, b;
#pragma unroll
    for (int k = 0; k < 4; ++k) {
        float t  = vv[k] * 4096.0f;
        float q0 = rintf(t);  float r = t - q0;
        float q1 = rintf(r * 128.0f);
        a[k] = (i8)(int)q0; b[k] = (i8)(int)q1;
    }
    *(i8x4*)(p0 + i) = a; *(i8x4*)(p1 + i) = b;
}

static constexpr int SB_W0 = 2048;
static constexpr int SB_W1 = 4096;
static constexpr int SB_W2 = 2048;
static constexpr int SB_X  = 6400;

__global__ void split_all(const float* __restrict__ w0, bf16* w0p0, bf16* w0p1, bf16* w0p2,
                          const float* __restrict__ w1, i8* w1q0, i8* w1q1, i8* w1q2,
                          const float* __restrict__ w2, i8* w2q0, i8* w2q1,
                          const float* __restrict__ x,  char* xp0, char* xp1, char* xp2) {
    int b = blockIdx.x;
    if (b < SB_W0) {
        split3_w0(w0, w0p0, w0p1, w0p2, b * 1024 + threadIdx.x * 4);
    } else if (b < SB_W0 + SB_W1) {
        spliti8_3(w1, w1q0, w1q1, w1q2, (b - SB_W0) * 1024 + threadIdx.x * 4);
    } else if (b < SB_W0 + SB_W1 + SB_W2) {
        spliti8_2(w2, w2q0, w2q1, (b - SB_W0 - SB_W1) * 1024 + threadIdx.x * 4);
    } else {
        split3_x(x, xp0, xp1, xp2, (b - SB_W0 - SB_W1 - SB_W2) * 1024 + threadIdx.x * 4);
    }
}

// ---------------------------------------------------------------------------
DEVFN void mfma16(f32x4 (&acc)[4][4], const bf16x8 (&a)[4], const bf16x8* b) {
    __builtin_amdgcn_s_setprio(1);
#pragma unroll
    for (int i = 0; i < 4; ++i)
#pragma unroll
        for (int j = 0; j < 4; ++j)
            acc[i][j] = __builtin_amdgcn_mfma_f32_16x16x32_bf16(a[i], b[j], acc[i][j], 0, 0, 0);
    __builtin_amdgcn_s_setprio(0);
}

DEVFN void frag4b(bf16x8* f, const bf16* s, int wrow, int fr, int fkS) {
#pragma unroll
    for (int i = 0; i < 4; ++i)
        f[i] = *(const bf16x8*)((const char*)s + (wrow + i * 16 + fr) * 64 + fkS);
}

// L0: bf16 6-pass, BK=32, B in LDS (dbuf 48K), A (x-planes) reg-loaded tiled.
__global__ __launch_bounds__(512, 2)
void gemm_l0(const char* __restrict__ A0, const char* __restrict__ A1,
             const char* __restrict__ A2, const bf16* __restrict__ B0,
             const bf16* __restrict__ B1, const bf16* __restrict__ B2,
             const float* __restrict__ bias, float* __restrict__ C,
             int M, int N, int K) {
    constexpr int BPL = 128 * 32;            // B plane elems (8 KiB)
    constexpr int BUF = 3 * BPL;
    __shared__ __align__(1024) bf16 lds[2 * BUF];   // 48 KiB

    const int t = threadIdx.x, lane = t & 63, wv = t >> 6;
    const int wm = (wv >> 1) * 64, wn = (wv & 1) * 64;
    const int bm = blockIdx.x * 256, bn = blockIdx.y * 128;
    const int sk = (wv >> 2) & 1;            // SIMD-partner stagger key
    const int fr = lane & 15, g = lane >> 4;
    const int fkS = (g ^ ((lane >> 1) & 3)) * 16;
    const int cr = g * 4, cc = fr;
    const int rb0 = blockIdx.x * 16 + (wv >> 1) * 4;   // A row-tile base
    const int lof = lane * 16;                         // lane offset in tile

    f32x4 accM[4][4] = {}, accS[4][4] = {};

    auto pB = [&](int p, int i) { return lds + p * BUF + i * BPL; };

    int offB;
    { int c = t, row = c >> 2, slot = c & 3;
      offB = (bn + row) * K + (slot ^ ((row >> 1) & 3)) * 8; }
    auto stB = [&](const bf16* gp, bf16* s, int k0) {
        llds16(gp + offB + k0, (char*)s + (t >> 6) * 1024);
    };
    // tiled A fragment load: 4 x 16B coalesced from global (L2-resident)
    auto ldA = [&](const char* P, int tb, bf16x8 (&f)[4]) {
#pragma unroll
        for (int i = 0; i < 4; ++i)
            f[i] = *(const bf16x8*)(P + tb + (i << 10) + lof);
    };

    stB(B0, pB(0, 0), 0); stB(B1, pB(0, 1), 0); stB(B2, pB(0, 2), 0);
    __syncthreads();

    const int NT = K / 32;
    int p = 0;
    for (int tt = 0; tt < NT; ++tt, p ^= 1) {
        const int q = p ^ 1, kn = (tt + 1) * 32;
        const bool pf = (tt + 1 < NT);
        const int tb = (tt * RBS + rb0) << 10;       // kb = tt for BK=32
        bf16x8 aX[4], aY[4], b0f[4], b1f[4], b2f[4];
        if (sk == 0) {
            ldA(A0, tb, aX);
            frag4b(b0f, pB(p, 0), wn, fr, fkS);
            mfma16(accM, aX, b0f);                    // a0b0
            ldA(A1, tb, aY);                          // early for P3/P4
            if (pf) stB(B0, pB(q, 0), kn);
            frag4b(b1f, pB(p, 1), wn, fr, fkS);
            mfma16(accS, aX, b1f);                    // a0b1
            if (pf) stB(B1, pB(q, 1), kn);
            frag4b(b2f, pB(p, 2), wn, fr, fkS);
            mfma16(accS, aX, b2f);                    // a0b2
            ldA(A2, tb, aX);                          // early for P5
            if (pf) stB(B2, pB(q, 2), kn);
            mfma16(accS, aY, b0f);                    // a1b0
            mfma16(accS, aY, b1f);                    // a1b1
            mfma16(accS, aX, b0f);                    // a2b0
        } else {
            ldA(A1, tb, aX);
            frag4b(b0f, pB(p, 0), wn, fr, fkS);
            mfma16(accS, aX, b0f);                    // a1b0
            ldA(A2, tb, aY);
            if (pf) stB(B0, pB(q, 0), kn);
            frag4b(b1f, pB(p, 1), wn, fr, fkS);
            mfma16(accS, aX, b1f);                    // a1b1
            if (pf) stB(B1, pB(q, 1), kn);
            mfma16(accS, aY, b0f);                    // a2b0
            ldA(A0, tb, aX);
            if (pf) stB(B2, pB(q, 2), kn);
            frag4b(b2f, pB(p, 2), wn, fr, fkS);
            mfma16(accM, aX, b0f);                    // a0b0
            mfma16(accS, aX, b1f);                    // a0b1
            mfma16(accS, aX, b2f);                    // a0b2
        }
        __syncthreads();
    }

#pragma unroll
    for (int j = 0; j < 4; ++j) {
        int col = bn + wn + j * 16 + cc;
        double bvs = (double)bias[col];
#pragma unroll
        for (int i = 0; i < 4; ++i) {
            int row0 = bm + wm + i * 16 + cr;
#pragma unroll
            for (int r = 0; r < 4; ++r) {
                double v = (double)accM[i][j][r] + (double)accS[i][j][r] + bvs;
                C[(size_t)(row0 + r) * N + col] = (float)v;
            }
        }
    }
}

// ---------------------------------------------------------------------------
// i8 GEMM (L1/L2): A = spikes tiled in global (reg-loaded), B digit planes in
// LDS (dbuf). BK=128, mfma_i32_16x16x64_i8, exact i32 acc. Numerics == R7.
template <int MODE>
__global__ __launch_bounds__(512, 2)
void gemm_i8(const i8* __restrict__ A, const i8* __restrict__ B0,
             const i8* __restrict__ B1, const i8* __restrict__ B2,
             const float* __restrict__ bias, float* __restrict__ C,
             int M, int N, int K) {
    constexpr int NP  = (MODE == 1) ? 3 : 2;
    constexpr int BN  = (MODE == 1) ? 64 : 128;
    constexpr int WNF = (MODE == 1) ? 2 : 4;     // 16-col frags per wave
    constexpr int BPL = BN * 128;                // B plane bytes (8K / 16K)
    constexpr int BUF = NP * BPL;                // 24K / 32K
    constexpr int BIT = (BN * 8) / 512;          // llds16 per plane (1 / 2)
    __shared__ __align__(1024) i8 lds[2 * BUF];  // 48K / 64K

    const int t = threadIdx.x, lane = t & 63, wv = t >> 6;
    const int wm = (wv >> 1) * 64, wn = (wv & 1) * (WNF * 16);
    const int bm = blockIdx.x * 256, bn = blockIdx.y * BN;
    const int fr = lane & 15, g = lane >> 4;
    const int fkA = (g ^ (lane & 7)) * 16;       // k-half 0 chunk, bytes
    const int fkB = ((4 + g) ^ (lane & 7)) * 16; // k-half 1
    const int cr = g * 4, cc = fr;
    const int rb0 = blockIdx.x * 16 + (wv >> 1) * 4;
    const int lof = lane * 16;

    i32x4 acc[NP][4][WNF] = {};

    int offB[BIT];
#pragma unroll
    for (int r = 0; r < BIT; ++r) {
        int c = t + r * 512, row = c >> 3, slot = c & 7;
        offB[r] = (bn + row) * K + (slot ^ (row & 7)) * 16;
    }
    auto stB = [&](const i8* gp, i8* s, int k0) {
#pragma unroll
        for (int r = 0; r < BIT; ++r)
            llds16(gp + offB[r] + k0, s + ((t + r * 512) >> 6) * 1024);
    };
    auto pBl = [&](int p, int pl) { return lds + p * BUF + pl * BPL; };
    auto ldA = [&](int kb, i32x4 (&f)[4]) {
#pragma unroll
        for (int i = 0; i < 4; ++i)
            f[i] = *(const i32x4*)(A + ((kb * RBS + rb0 + i) << 10) + lof);
    };

    stB(B0, pBl(0, 0), 0);
    stB(B1, pBl(0, 1), 0);
    if constexpr (NP == 3) stB(B2, pBl(0, 2), 0);
    __syncthreads();

    const int NT = K / 128;
    int p = 0;
    for (int tt = 0; tt < NT; ++tt, p ^= 1) {
        const int q = p ^ 1, kn = (tt + 1) * 128;
        const bool pf = (tt + 1 < NT);
        i32x4 avX[4], avY[4], bvf[NP][WNF];
        ldA(tt * 2 + 0, avX);                    // kh0 A frags
        ldA(tt * 2 + 1, avY);                    // kh1 A frags (early issue)
        // kh0
#pragma unroll
        for (int pl = 0; pl < NP; ++pl) {
            const i8* sB = pBl(p, pl);
#pragma unroll
            for (int j = 0; j < WNF; ++j)
                bvf[pl][j] = *(const i32x4*)(sB + (wn + j * 16 + fr) * 128 + fkA);
        }
        if (pf) {
            stB(B0, pBl(q, 0), kn);
            stB(B1, pBl(q, 1), kn);
            if constexpr (NP == 3) stB(B2, pBl(q, 2), kn);
        }
        __builtin_amdgcn_s_setprio(1);
#pragma unroll
        for (int pl = 0; pl < NP; ++pl)
#pragma unroll
            for (int i = 0; i < 4; ++i)
#pragma unroll
                for (int j = 0; j < WNF; ++j)
                    acc[pl][i][j] = __builtin_amdgcn_mfma_i32_16x16x64_i8(
                        avX[i], bvf[pl][j], acc[pl][i][j], 0, 0, 0);
        __builtin_amdgcn_s_setprio(0);
        // kh1
#pragma unroll
        for (int pl = 0; pl < NP; ++pl) {
            const i8* sB = pBl(p, pl);
#pragma unroll
            for (int j = 0; j < WNF; ++j)
                bvf[pl][j] = *(const i32x4*)(sB + (wn + j * 16 + fr) * 128 + fkB);
        }
        __builtin_amdgcn_s_setprio(1);
#pragma unroll
        for (int pl = 0; pl < NP; ++pl)
#pragma unroll
            for (int i = 0; i < 4; ++i)
#pragma unroll
                for (int j = 0; j < WNF; ++j)
                    acc[pl][i][j] = __builtin_amdgcn_mfma_i32_16x16x64_i8(
                        avY[i], bvf[pl][j], acc[pl][i][j], 0, 0, 0);
        __builtin_amdgcn_s_setprio(0);
        __syncthreads();
    }

    // exact integer dots merged in fp64: cur = (d0 + d1/128 [+ d2/16384])/4096 + b
#pragma unroll
    for (int j = 0; j < WNF; ++j) {
        int col = bn + wn + j * 16 + cc;
        double bvs = (double)bias[col];
#pragma unroll
        for (int i = 0; i < 4; ++i) {
            int row0 = bm + wm + i * 16 + cr;
#pragma unroll
            for (int r = 0; r < 4; ++r) {
                double v = (double)acc[0][i][j][r] + (double)acc[1][i][j][r] * (1.0 / 128.0);
                if constexpr (NP == 3) v += (double)acc[2][i][j][r] * (1.0 / 16384.0);
                C[(size_t)(row0 + r) * N + col] = (float)(v * (1.0 / 4096.0) + bvs);
            }
        }
    }
}

// ---------------------------------------------------------------------------
// LIF scans — fp64 recurrence (verified). Hidden spikes written TILED i8
// (feeds the reg-A i8 GEMMs): addr = base0 + t*16384.
template <int F>
__global__ void lif_hidden(const float* __restrict__ cur, i8* __restrict__ spk) {
    const int tid = blockIdx.x * 256 + threadIdx.x;  // b*F + f
    const int b = tid >> 11, f = tid & 2047;
    const int base0 = (((f >> 6) * RBS + (b >> 4)) << 10)
                    | (((f >> 4) & 3) << 8) | ((b & 15) << 4) | (f & 15);
    double m = 0.0;
    size_t off = tid;
#pragma unroll
    for (int t = 0; t < T_STEPS; ++t) {
        m = 0.9 * m + (double)cur[off];
        bool s = (m - 1.0) > 0.0;
        spk[base0 + t * 16384] = s ? (i8)1 : (i8)0;
        if (s) m -= 1.0;
        off += (size_t)BATCH * F;
    }
}

__global__ void lif_out(const float* __restrict__ cur, float* __restrict__ out) {
    const int tid = blockIdx.x * 256 + threadIdx.x;  // b*1024 + f
    double m = 0.0;
    size_t off = tid;
#pragma unroll
    for (int t = 0; t < T_STEPS; ++t) {
        m = 0.9 * m + (double)cur[off];
        bool s = (m - 1.0) > 0.0;
        out[off] = s ? 1.0f : 0.0f;
        if (s) m -= 1.0;
        off += (size_t)BATCH * 1024;
    }
    out[(size_t)T_STEPS * BATCH * 1024 + tid] = (float)m;  // final membrane (output 1)
}

// ---------------------------------------------------------------------------
extern "C" void kernel_launch(void* const* d_in, const int* in_sizes, int n_in,
                              void* d_out, int out_size, void* d_ws, size_t ws_size,
                              hipStream_t stream) {
    const float* xin = (const float*)d_in[0];
    const float* w0  = (const float*)d_in[1];
    const float* b0  = (const float*)d_in[2];
    const float* w1  = (const float*)d_in[3];
    const float* b1  = (const float*)d_in[4];
    const float* w2  = (const float*)d_in[5];
    const float* b2  = (const float*)d_in[6];
    float* out = (float*)d_out;

    constexpr size_t NW0 = 2048 * 1024;
    constexpr size_t NW1 = 2048 * 2048;
    constexpr size_t NW2 = 1024 * 2048;
    constexpr size_t NX  = (size_t)MROWS * 1024;  // 6,553,600
    constexpr size_t NH  = (size_t)MROWS * 2048;  // 13,107,200

    char* ws = (char*)d_ws;
    size_t off = 0;
    auto carve = [&](size_t bytes) { char* p = ws + off; off += bytes; return p; };

    // long-lived planes: w1 -> 3 i8 digit planes, w2 -> 2 (row-major, B ops)
    i8* w1q0 = (i8*)carve(NW1);
    i8* w1q1 = (i8*)carve(NW1);
    i8* w1q2 = (i8*)carve(NW1);
    i8* w2q0 = (i8*)carve(NW2);
    i8* w2q1 = (i8*)carve(NW2);
    // pool: w0 bf16 planes + tiled x planes live only until G0; s0/s1 after
    char* pool = carve(2 * NH * 2);          // 52,428,800 B
    bf16* w0p0 = (bf16*)pool;
    bf16* w0p1 = w0p0 + NW0;
    bf16* w0p2 = w0p1 + NW0;
    char* xp0  = (char*)(w0p2 + NW0);        // tiled, NX*2 bytes each
    char* xp1  = xp0 + NX * 2;
    char* xp2  = xp1 + NX * 2;               // ends at pool + 51,904,512
    i8* s0 = (i8*)pool;                      // tiled spikes, after G0 consumed
    i8* s1 = s0 + NH;
    float* cur = (float*)carve(NH * 4);
    if (ws_size < off) return;               // ~121 MB total

    // 1) fused precision splits (one launch)
    split_all<<<SB_W0 + SB_W1 + SB_W2 + SB_X, 256, 0, stream>>>(
        w0, w0p0, w0p1, w0p2, w1, w1q0, w1q1, w1q2,
        w2, w2q0, w2q1, xin, xp0, xp1, xp2);

    // 2) layer 0: cur0 = x @ W0^T + b0 (bf16 6-pass, reg-A tiled x)
    gemm_l0<<<dim3(25, 16), 512, 0, stream>>>(xp0, xp1, xp2, w0p0, w0p1, w0p2,
                                              b0, cur, MROWS, 2048, 1024);
    lif_hidden<2048><<<(BATCH * 2048) / 256, 256, 0, stream>>>(cur, s0);

    // 3) layer 1: cur1 = s0 @ W1^T + b1 (i8 3-plane, reg-A tiled spikes)
    gemm_i8<1><<<dim3(25, 32), 512, 0, stream>>>(s0, w1q0, w1q1, w1q2,
                                                 b1, cur, MROWS, 2048, 2048);
    lif_hidden<2048><<<(BATCH * 2048) / 256, 256, 0, stream>>>(cur, s1);

    // 4) layer 2: cur2 = s1 @ W2^T + b2 (i8 2-plane)
    gemm_i8<2><<<dim3(25, 8), 512, 0, stream>>>(s1, w2q0, w2q1, nullptr,
                                                b2, cur, MROWS, 1024, 2048);
    lif_out<<<(BATCH * 1024) / 256, 256, 0, stream>>>(cur, out);
}

// Round 9
// 425.968 us; speedup vs baseline: 1.1527x; 1.1527x over previous
//
#include <hip/hip_runtime.h>
#include <hip/hip_bf16.h>

typedef __bf16 bf16;
typedef __bf16 bf16x4 __attribute__((ext_vector_type(4)));
typedef __bf16 bf16x8 __attribute__((ext_vector_type(8)));
typedef float  f32x4  __attribute__((ext_vector_type(4)));
typedef signed char i8;
typedef signed char i8x4 __attribute__((ext_vector_type(4)));
typedef int    i32x4 __attribute__((ext_vector_type(4)));

#define DEVFN static __device__ __forceinline__

static constexpr int T_STEPS = 25;
static constexpr int BATCH   = 256;
static constexpr int MROWS   = T_STEPS * BATCH;  // 6400
static constexpr int RBS     = MROWS / 16;       // 400 row-tiles

// async global->LDS, 16B/lane; LDS base must be wave-uniform (HW adds lane*16).
DEVFN void llds16(const void* g, void* l) {
    __builtin_amdgcn_global_load_lds(
        (const __attribute__((address_space(1))) void*)g,
        (__attribute__((address_space(3))) void*)l, 16, 0, 0);
}

// ---------------------------------------------------------------------------
// Precision splits (R7-verified numerics).
DEVFN void split3_chunk(const float* src, bf16* p0, bf16* p1, bf16* p2, int i) {
    float4 v = *(const float4*)(src + i);
    float vv[4] = {v.x, v.y, v.z, v.w};
    bf16x4 a, b, c;
#pragma unroll
    for (int k = 0; k < 4; ++k) {
        bf16 h0 = (bf16)vv[k];
        float r1 = vv[k] - (float)h0;      // exact
        bf16 h1 = (bf16)r1;
        float r2 = r1 - (float)h1;         // exact
        a[k] = h0; b[k] = h1; c[k] = (bf16)r2;
    }
    *(bf16x4*)(p0 + i) = a;
    *(bf16x4*)(p1 + i) = b;
    *(bf16x4*)(p2 + i) = c;
}

DEVFN void spliti8_3(const float* src, i8* p0, i8* p1, i8* p2, int i) {
    float4 v = *(const float4*)(src + i);
    float vv[4] = {v.x, v.y, v.z, v.w};
    i8x4 a, b, c;
#pragma unroll
    for (int k = 0; k < 4; ++k) {
        float t  = vv[k] * 4096.0f;              // exact (pow2)
        float q0 = rintf(t);  float r = t - q0;             // exact
        float q1 = rintf(r * 128.0f); r = r * 128.0f - q1;  // exact
        float q2 = rintf(r * 128.0f);
        a[k] = (i8)(int)q0; b[k] = (i8)(int)q1; c[k] = (i8)(int)q2;
    }
    *(i8x4*)(p0 + i) = a; *(i8x4*)(p1 + i) = b; *(i8x4*)(p2 + i) = c;
}

DEVFN void spliti8_2(const float* src, i8* p0, i8* p1, int i) {
    float4 v = *(const float4*)(src + i);
    float vv[4] = {v.x, v.y, v.z, v.w};
    i8x4 a, b;
#pragma unroll
    for (int k = 0; k < 4; ++k) {
        float t  = vv[k] * 4096.0f;
        float q0 = rintf(t);  float r = t - q0;
        float q1 = rintf(r * 128.0f);
        a[k] = (i8)(int)q0; b[k] = (i8)(int)q1;
    }
    *(i8x4*)(p0 + i) = a; *(i8x4*)(p1 + i) = b;
}

static constexpr int SB_W0 = 2048;
static constexpr int SB_W1 = 4096;
static constexpr int SB_W2 = 2048;
static constexpr int SB_X  = 6400;

__global__ void split_all(const float* __restrict__ w0, bf16* w0p0, bf16* w0p1, bf16* w0p2,
                          const float* __restrict__ w1, i8* w1q0, i8* w1q1, i8* w1q2,
                          const float* __restrict__ w2, i8* w2q0, i8* w2q1,
                          const float* __restrict__ x,  bf16* xp0,  bf16* xp1,  bf16* xp2) {
    int b = blockIdx.x;
    if (b < SB_W0) {
        split3_chunk(w0, w0p0, w0p1, w0p2, b * 1024 + threadIdx.x * 4);
    } else if (b < SB_W0 + SB_W1) {
        spliti8_3(w1, w1q0, w1q1, w1q2, (b - SB_W0) * 1024 + threadIdx.x * 4);
    } else if (b < SB_W0 + SB_W1 + SB_W2) {
        spliti8_2(w2, w2q0, w2q1, (b - SB_W0 - SB_W1) * 1024 + threadIdx.x * 4);
    } else {
        split3_chunk(x, xp0, xp1, xp2, (b - SB_W0 - SB_W1 - SB_W2) * 1024 + threadIdx.x * 4);
    }
}

// ---------------------------------------------------------------------------
// L0 GEMM: exact R7 version (LDS A, 144K dbuf, stagger; 157us verified x3).
DEVFN void mfma16(f32x4 (&acc)[4][4], const bf16x8* a, const bf16x8* b) {
    __builtin_amdgcn_s_setprio(1);
#pragma unroll
    for (int i = 0; i < 4; ++i)
#pragma unroll
        for (int j = 0; j < 4; ++j)
            acc[i][j] = __builtin_amdgcn_mfma_f32_16x16x32_bf16(a[i], b[j], acc[i][j], 0, 0, 0);
    __builtin_amdgcn_s_setprio(0);
}

DEVFN void frag4b(bf16x8* f, const bf16* s, int wrow, int fr, int fkS) {
#pragma unroll
    for (int i = 0; i < 4; ++i)
        f[i] = *(const bf16x8*)((const char*)s + (wrow + i * 16 + fr) * 64 + fkS);
}

__global__ __launch_bounds__(512, 2)
void gemm_l0(const bf16* __restrict__ A0, const bf16* __restrict__ A1,
             const bf16* __restrict__ A2, const bf16* __restrict__ B0,
             const bf16* __restrict__ B1, const bf16* __restrict__ B2,
             const float* __restrict__ bias, float* __restrict__ C,
             int M, int N, int K) {
    constexpr int APL = 256 * 32;            // A plane elems (16 KiB)
    constexpr int BPL = 128 * 32;            // B plane elems ( 8 KiB)
    constexpr int BUF = 3 * APL + 3 * BPL;
    __shared__ __align__(1024) bf16 lds[2 * BUF];   // 144 KiB

    const int t = threadIdx.x, lane = t & 63, wv = t >> 6;
    const int wm = (wv >> 1) * 64, wn = (wv & 1) * 64;
    const int bm = blockIdx.x * 256, bn = blockIdx.y * 128;
    const int sk = (wv >> 2) & 1;            // SIMD-partner stagger key
    const int fr = lane & 15, g = lane >> 4;
    const int fkS = (g ^ ((lane >> 1) & 3)) * 16;
    const int cr = g * 4, cc = fr;

    f32x4 accM[4][4] = {}, accS[4][4] = {};

    auto pA = [&](int p, int i) { return lds + p * BUF + i * APL; };
    auto pB = [&](int p, int i) { return lds + p * BUF + 3 * APL + i * BPL; };

    int offA[2], offB[1];
#pragma unroll
    for (int r = 0; r < 2; ++r) {
        int c = t + r * 512, row = c >> 2, slot = c & 3;
        offA[r] = (bm + row) * K + (slot ^ ((row >> 1) & 3)) * 8;
    }
    {
        int c = t, row = c >> 2, slot = c & 3;
        offB[0] = (bn + row) * K + (slot ^ ((row >> 1) & 3)) * 8;
    }
    auto stA = [&](const bf16* gp, bf16* s, int k0) {
#pragma unroll
        for (int r = 0; r < 2; ++r)
            llds16(gp + offA[r] + k0, (char*)s + ((t + r * 512) >> 6) * 1024);
    };
    auto stB = [&](const bf16* gp, bf16* s, int k0) {
        llds16(gp + offB[0] + k0, (char*)s + (t >> 6) * 1024);
    };

    stA(A0, pA(0, 0), 0); stA(A1, pA(0, 1), 0); stA(A2, pA(0, 2), 0);
    stB(B0, pB(0, 0), 0); stB(B1, pB(0, 1), 0); stB(B2, pB(0, 2), 0);
    __syncthreads();

    const int NT = K / 32;
    int p = 0;
    for (int tt = 0; tt < NT; ++tt, p ^= 1) {
        const int q = p ^ 1, kn = (tt + 1) * 32;
        const bool pf = (tt + 1 < NT);
        bf16x8 a[4], b0f[4], b1f[4], b2f[4];
        if (sk == 0) {
            frag4b(a,   pA(p, 0), wm, fr, fkS);
            frag4b(b0f, pB(p, 0), wn, fr, fkS);
            if (pf) stA(A0, pA(q, 0), kn);
            mfma16(accM, a, b0f);                        // a0b0
            if (pf) { stA(A1, pA(q, 1), kn); stA(A2, pA(q, 2), kn); }
            frag4b(b1f, pB(p, 1), wn, fr, fkS);
            mfma16(accS, a, b1f);                        // a0b1
            if (pf) { stB(B0, pB(q, 0), kn); stB(B1, pB(q, 1), kn); stB(B2, pB(q, 2), kn); }
            frag4b(b2f, pB(p, 2), wn, fr, fkS);
            mfma16(accS, a, b2f);                        // a0b2
            frag4b(a, pA(p, 1), wm, fr, fkS);
            mfma16(accS, a, b0f);                        // a1b0
            mfma16(accS, a, b1f);                        // a1b1
            frag4b(a, pA(p, 2), wm, fr, fkS);
            mfma16(accS, a, b0f);                        // a2b0
        } else {
            frag4b(a,   pA(p, 1), wm, fr, fkS);          // a1
            frag4b(b0f, pB(p, 0), wn, fr, fkS);
            if (pf) stA(A0, pA(q, 0), kn);
            mfma16(accS, a, b0f);                        // a1b0
            if (pf) { stA(A1, pA(q, 1), kn); stA(A2, pA(q, 2), kn); }
            frag4b(b1f, pB(p, 1), wn, fr, fkS);
            mfma16(accS, a, b1f);                        // a1b1
            if (pf) { stB(B0, pB(q, 0), kn); stB(B1, pB(q, 1), kn); stB(B2, pB(q, 2), kn); }
            frag4b(a, pA(p, 2), wm, fr, fkS);
            mfma16(accS, a, b0f);                        // a2b0
            frag4b(a, pA(p, 0), wm, fr, fkS);            // a0
            mfma16(accM, a, b0f);                        // a0b0
            frag4b(b2f, pB(p, 2), wn, fr, fkS);
            mfma16(accS, a, b1f);                        // a0b1
            mfma16(accS, a, b2f);                        // a0b2
        }
        __syncthreads();
    }

#pragma unroll
    for (int j = 0; j < 4; ++j) {
        int col = bn + wn + j * 16 + cc;
        double bvs = (double)bias[col];
#pragma unroll
        for (int i = 0; i < 4; ++i) {
            int row0 = bm + wm + i * 16 + cr;
#pragma unroll
            for (int r = 0; r < 4; ++r) {
                double v = (double)accM[i][j][r] + (double)accS[i][j][r] + bvs;
                C[(size_t)(row0 + r) * N + col] = (float)v;
            }
        }
    }
}

// ---------------------------------------------------------------------------
// L1 i8 GEMM (NEW R9): A = spikes TILED in global (layout R8-verified
// bit-correct), loaded to regs with ONE-BODY PREFETCH (flight = full body,
// the discipline R8 missed). B digit planes in LDS dbuf. LDS/body 216->120KB.
__global__ __launch_bounds__(512, 2)
void gemm_i8r(const i8* __restrict__ A, const i8* __restrict__ B0,
              const i8* __restrict__ B1, const i8* __restrict__ B2,
              const float* __restrict__ bias, float* __restrict__ C,
              int M, int N, int K) {
    constexpr int BPL = 64 * 128;                // B plane bytes (8K)
    constexpr int BUF = 3 * BPL;                 // 24K
    __shared__ __align__(1024) i8 lds[2 * BUF];  // 48K

    const int t = threadIdx.x, lane = t & 63, wv = t >> 6;
    const int wm = (wv >> 1) * 64, wn = (wv & 1) * 32;
    const int bm = blockIdx.x * 256, bn = blockIdx.y * 64;
    const int fr = lane & 15, g = lane >> 4;
    const int fkA = (g ^ (lane & 7)) * 16;       // k-half 0 chunk, bytes
    const int fkB = ((4 + g) ^ (lane & 7)) * 16; // k-half 1
    const int cr = g * 4, cc = fr;
    const int rb0 = blockIdx.x * 16 + (wv >> 1) * 4;
    const int lof = lane * 16;

    i32x4 acc[3][4][2] = {};

    int offB;
    { int c = t, row = c >> 3, slot = c & 7;
      offB = (bn + row) * K + (slot ^ (row & 7)) * 16; }
    auto stB = [&](const i8* gp, i8* s, int k0) {
        llds16(gp + offB + k0, s + (t >> 6) * 1024);
    };
    auto pBl = [&](int p, int pl) { return lds + p * BUF + pl * BPL; };
    auto ldA = [&](int kb, i32x4 (&f)[4]) {
#pragma unroll
        for (int i = 0; i < 4; ++i)
            f[i] = *(const i32x4*)(A + ((kb * RBS + rb0 + i) << 10) + lof);
    };

    // prologue: body-0 B into buf 0, body-0 A frags into regs
    stB(B0, pBl(0, 0), 0);
    stB(B1, pBl(0, 1), 0);
    stB(B2, pBl(0, 2), 0);
    i32x4 aA0[4], aA1[4], aB0[4], aB1[4];
    ldA(0, aA0); ldA(1, aA1);
    __syncthreads();

    const int NT = K / 128;                      // 16 (even)
    auto body = [&](int tt, int p, i32x4 (&c0)[4], i32x4 (&c1)[4],
                    i32x4 (&n0)[4], i32x4 (&n1)[4]) {
        const int q = p ^ 1, kn = (tt + 1) * 128;
        const bool pf = (tt + 1 < NT);
        // prefetch NEXT body's A frags (consumed next body -> 1-body flight)
        if (pf) { ldA((tt + 1) * 2, n0); ldA((tt + 1) * 2 + 1, n1); }
        i32x4 bvf[3][2];
#pragma unroll
        for (int pl = 0; pl < 3; ++pl) {
            const i8* sB = pBl(p, pl);
#pragma unroll
            for (int j = 0; j < 2; ++j)
                bvf[pl][j] = *(const i32x4*)(sB + (wn + j * 16 + fr) * 128 + fkA);
        }
        if (pf) { stB(B0, pBl(q, 0), kn); stB(B1, pBl(q, 1), kn); stB(B2, pBl(q, 2), kn); }
        __builtin_amdgcn_s_setprio(1);
#pragma unroll
        for (int pl = 0; pl < 3; ++pl)
#pragma unroll
            for (int i = 0; i < 4; ++i)
#pragma unroll
                for (int j = 0; j < 2; ++j)
                    acc[pl][i][j] = __builtin_amdgcn_mfma_i32_16x16x64_i8(
                        c0[i], bvf[pl][j], acc[pl][i][j], 0, 0, 0);
        __builtin_amdgcn_s_setprio(0);
#pragma unroll
        for (int pl = 0; pl < 3; ++pl) {
            const i8* sB = pBl(p, pl);
#pragma unroll
            for (int j = 0; j < 2; ++j)
                bvf[pl][j] = *(const i32x4*)(sB + (wn + j * 16 + fr) * 128 + fkB);
        }
        __builtin_amdgcn_s_setprio(1);
#pragma unroll
        for (int pl = 0; pl < 3; ++pl)
#pragma unroll
            for (int i = 0; i < 4; ++i)
#pragma unroll
                for (int j = 0; j < 2; ++j)
                    acc[pl][i][j] = __builtin_amdgcn_mfma_i32_16x16x64_i8(
                        c1[i], bvf[pl][j], acc[pl][i][j], 0, 0, 0);
        __builtin_amdgcn_s_setprio(0);
        __syncthreads();
    };
    int p = 0;
    for (int tt = 0; tt < NT; tt += 2) {         // 2x unroll: name-swapped A bufs
        body(tt,     p, aA0, aA1, aB0, aB1); p ^= 1;
        body(tt + 1, p, aB0, aB1, aA0, aA1); p ^= 1;
    }

    // exact integer dots merged in fp64
#pragma unroll
    for (int j = 0; j < 2; ++j) {
        int col = bn + wn + j * 16 + cc;
        double bvs = (double)bias[col];
#pragma unroll
        for (int i = 0; i < 4; ++i) {
            int row0 = bm + wm + i * 16 + cr;
#pragma unroll
            for (int r = 0; r < 4; ++r) {
                double v = (double)acc[0][i][j][r] + (double)acc[1][i][j][r] * (1.0 / 128.0)
                         + (double)acc[2][i][j][r] * (1.0 / 16384.0);
                C[(size_t)(row0 + r) * N + col] = (float)(v * (1.0 / 4096.0) + bvs);
            }
        }
    }
}

// ---------------------------------------------------------------------------
// L2 i8 GEMM: exact R7 version (LDS-A, row-major s1). Small kernel; verified.
__global__ __launch_bounds__(512, 2)
void gemm_i8_l2(const i8* __restrict__ A, const i8* __restrict__ B0,
                const i8* __restrict__ B1,
                const float* __restrict__ bias, float* __restrict__ C,
                int M, int N, int K) {
    constexpr int NP  = 2;
    constexpr int BN  = 128;
    constexpr int WNF = 4;
    constexpr int BK  = 128;
    constexpr int APL = 256 * BK;
    constexpr int BPL = BN * BK;
    constexpr int BUF = APL + NP * BPL;          // 64K
    constexpr int AIT = 4;
    constexpr int BIT = 2;
    __shared__ __align__(1024) i8 lds[2 * BUF];  // 128K

    const int t = threadIdx.x, lane = t & 63, wv = t >> 6;
    const int wm = (wv >> 1) * 64, wn = (wv & 1) * (WNF * 16);
    const int bm = blockIdx.x * 256, bn = blockIdx.y * BN;
    const int fr = lane & 15, g = lane >> 4;
    const int fkA = (g ^ (lane & 7)) * 16;
    const int fkB = ((4 + g) ^ (lane & 7)) * 16;
    const int cr = g * 4, cc = fr;

    i32x4 acc[NP][4][WNF] = {};

    int offA[AIT], offB[BIT];
#pragma unroll
    for (int r = 0; r < AIT; ++r) {
        int c = t + r * 512, row = c >> 3, slot = c & 7;
        offA[r] = (bm + row) * K + (slot ^ (row & 7)) * 16;
    }
#pragma unroll
    for (int r = 0; r < BIT; ++r) {
        int c = t + r * 512, row = c >> 3, slot = c & 7;
        offB[r] = (bn + row) * K + (slot ^ (row & 7)) * 16;
    }
    auto stA = [&](const i8* gp, i8* s, int k0) {
#pragma unroll
        for (int r = 0; r < AIT; ++r)
            llds16(gp + offA[r] + k0, s + ((t + r * 512) >> 6) * 1024);
    };
    auto stB = [&](const i8* gp, i8* s, int k0) {
#pragma unroll
        for (int r = 0; r < BIT; ++r)
            llds16(gp + offB[r] + k0, s + ((t + r * 512) >> 6) * 1024);
    };
    auto pAl = [&](int p) { return lds + p * BUF; };
    auto pBl = [&](int p, int pl) { return lds + p * BUF + APL + pl * BPL; };

    stA(A, pAl(0), 0);
    stB(B0, pBl(0, 0), 0);
    stB(B1, pBl(0, 1), 0);
    __syncthreads();

    const int NT = K / BK;
    int p = 0;
    for (int tt = 0; tt < NT; ++tt, p ^= 1) {
        const int q = p ^ 1, kn = (tt + 1) * BK;
        const bool pf = (tt + 1 < NT);
        const i8* sA = pAl(p);
        i32x4 av[4], bvf[NP][WNF];
#pragma unroll
        for (int kh = 0; kh < 2; ++kh) {
            const int fk = kh ? fkB : fkA;
#pragma unroll
            for (int i = 0; i < 4; ++i)
                av[i] = *(const i32x4*)(sA + (wm + i * 16 + fr) * 128 + fk);
            if (kh == 0 && pf) stA(A, pAl(q), kn);
#pragma unroll
            for (int pl = 0; pl < NP; ++pl) {
                const i8* sB = pBl(p, pl);
#pragma unroll
                for (int j = 0; j < WNF; ++j)
                    bvf[pl][j] = *(const i32x4*)(sB + (wn + j * 16 + fr) * 128 + fk);
            }
            if (kh == 0 && pf) {
                stB(B0, pBl(q, 0), kn);
                stB(B1, pBl(q, 1), kn);
            }
            __builtin_amdgcn_s_setprio(1);
#pragma unroll
            for (int pl = 0; pl < NP; ++pl)
#pragma unroll
                for (int i = 0; i < 4; ++i)
#pragma unroll
                    for (int j = 0; j < WNF; ++j)
                        acc[pl][i][j] = __builtin_amdgcn_mfma_i32_16x16x64_i8(
                            av[i], bvf[pl][j], acc[pl][i][j], 0, 0, 0);
            __builtin_amdgcn_s_setprio(0);
        }
        __syncthreads();
    }

#pragma unroll
    for (int j = 0; j < WNF; ++j) {
        int col = bn + wn + j * 16 + cc;
        double bvs = (double)bias[col];
#pragma unroll
        for (int i = 0; i < 4; ++i) {
            int row0 = bm + wm + i * 16 + cr;
#pragma unroll
            for (int r = 0; r < 4; ++r) {
                double v = (double)acc[0][i][j][r] + (double)acc[1][i][j][r] * (1.0 / 128.0);
                C[(size_t)(row0 + r) * N + col] = (float)(v * (1.0 / 4096.0) + bvs);
            }
        }
    }
}

// ---------------------------------------------------------------------------
// LIF scans — fp64 recurrence (verified). TILED=true writes the i8-tile
// layout (R8-verified bit-correct) for the reg-A L1 GEMM; else row-major.
template <int F, bool TILED>
__global__ void lif_hidden(const float* __restrict__ cur, i8* __restrict__ spk) {
    const int tid = blockIdx.x * 256 + threadIdx.x;  // b*F + f
    const int b = tid >> 11, f = tid & 2047;
    const int base0 = (((f >> 6) * RBS + (b >> 4)) << 10)
                    | (((f >> 4) & 3) << 8) | ((b & 15) << 4) | (f & 15);
    double m = 0.0;
    size_t off = tid;
#pragma unroll
    for (int t = 0; t < T_STEPS; ++t) {
        m = 0.9 * m + (double)cur[off];
        bool s = (m - 1.0) > 0.0;
        if constexpr (TILED) spk[base0 + t * 16384] = s ? (i8)1 : (i8)0;
        else                 spk[off] = s ? (i8)1 : (i8)0;
        if (s) m -= 1.0;
        off += (size_t)BATCH * F;
    }
}

__global__ void lif_out(const float* __restrict__ cur, float* __restrict__ out) {
    const int tid = blockIdx.x * 256 + threadIdx.x;  // b*1024 + f
    double m = 0.0;
    size_t off = tid;
#pragma unroll
    for (int t = 0; t < T_STEPS; ++t) {
        m = 0.9 * m + (double)cur[off];
        bool s = (m - 1.0) > 0.0;
        out[off] = s ? 1.0f : 0.0f;
        if (s) m -= 1.0;
        off += (size_t)BATCH * 1024;
    }
    out[(size_t)T_STEPS * BATCH * 1024 + tid] = (float)m;  // final membrane (output 1)
}

// ---------------------------------------------------------------------------
extern "C" void kernel_launch(void* const* d_in, const int* in_sizes, int n_in,
                              void* d_out, int out_size, void* d_ws, size_t ws_size,
                              hipStream_t stream) {
    const float* xin = (const float*)d_in[0];
    const float* w0  = (const float*)d_in[1];
    const float* b0  = (const float*)d_in[2];
    const float* w1  = (const float*)d_in[3];
    const float* b1  = (const float*)d_in[4];
    const float* w2  = (const float*)d_in[5];
    const float* b2  = (const float*)d_in[6];
    float* out = (float*)d_out;

    constexpr size_t NW0 = 2048 * 1024;
    constexpr size_t NW1 = 2048 * 2048;
    constexpr size_t NW2 = 1024 * 2048;
    constexpr size_t NX  = (size_t)MROWS * 1024;  // 6,553,600
    constexpr size_t NH  = (size_t)MROWS * 2048;  // 13,107,200

    char* ws = (char*)d_ws;
    size_t off = 0;
    auto carve = [&](size_t bytes) { char* p = ws + off; off += bytes; return p; };

    // long-lived planes: w1 -> 3 i8 digit planes, w2 -> 2 (row-major, B ops)
    i8* w1q0 = (i8*)carve(NW1);
    i8* w1q1 = (i8*)carve(NW1);
    i8* w1q2 = (i8*)carve(NW1);
    i8* w2q0 = (i8*)carve(NW2);
    i8* w2q1 = (i8*)carve(NW2);
    // pool: w0 bf16 planes + x bf16 planes live only until G0; s0/s1 (i8) after
    char* pool = carve(2 * NH * 2);          // 52,428,800 B
    bf16* w0p0 = (bf16*)pool;
    bf16* w0p1 = w0p0 + NW0;
    bf16* w0p2 = w0p1 + NW0;
    bf16* xp0  = w0p2 + NW0;
    bf16* xp1  = xp0 + NX;
    bf16* xp2  = xp1 + NX;                   // ends at pool + 51,904,512
    i8* s0 = (i8*)pool;                      // tiled spikes (L1 reg-A)
    i8* s1 = s0 + NH;                        // row-major spikes (L2 LDS-A)
    float* cur = (float*)carve(NH * 4);
    if (ws_size < off) return;               // ~121 MB total

    // 1) fused precision splits (one launch)
    split_all<<<SB_W0 + SB_W1 + SB_W2 + SB_X, 256, 0, stream>>>(
        w0, w0p0, w0p1, w0p2, w1, w1q0, w1q1, w1q2,
        w2, w2q0, w2q1, xin, xp0, xp1, xp2);

    // 2) layer 0: cur0 = x @ W0^T + b0 (bf16 6-pass, LDS-A, R7-verified)
    gemm_l0<<<dim3(25, 16), 512, 0, stream>>>(xp0, xp1, xp2, w0p0, w0p1, w0p2,
                                              b0, cur, MROWS, 2048, 1024);
    lif_hidden<2048, true><<<(BATCH * 2048) / 256, 256, 0, stream>>>(cur, s0);

    // 3) layer 1: cur1 = s0 @ W1^T + b1 (i8 3-plane, reg-A + 1-body prefetch)
    gemm_i8r<<<dim3(25, 32), 512, 0, stream>>>(s0, w1q0, w1q1, w1q2,
                                               b1, cur, MROWS, 2048, 2048);
    lif_hidden<2048, false><<<(BATCH * 2048) / 256, 256, 0, stream>>>(cur, s1);

    // 4) layer 2: cur2 = s1 @ W2^T + b2 (i8 2-plane, LDS-A, R7-verified)
    gemm_i8_l2<<<dim3(25, 8), 512, 0, stream>>>(s1, w2q0, w2q1,
                                                b2, cur, MROWS, 1024, 2048);
    lif_out<<<(BATCH * 1024) / 256, 256, 0, stream>>>(cur, out);
}